// Round 1
// baseline (156.932 us; speedup 1.0000x reference)
//
#include <hip/hip_runtime.h>
#include <hip/hip_bf16.h>

// Data_augV4: out[b] = t1(t0(x[b])), t from samples[(step, b)], 8 transforms.
// prob input is dead code in the reference (distrib computed, never used).
//
// Decomposition: flips (tf 1,2) are index-permutations that commute with all
// pointwise ops (contrast mean is flip-invariant) -> compose to XOR'd flip
// flags applied at the read address. Pointwise chain P1(P0(v)) applied in one
// fused pass. Contrast (tf 4) needs per-image mean of its input:
//   mean0 = mean(x[b])            (needed if t0==4, or t1==4 with t0 a flip)
//   mean1 = mean(P0(x[b]))        (needed if t1==4 and t0 pointwise)
// -> kernel1: per-image sum of x (early-exit unless needed)
//    kernel2: per-image sum of P0(x) (early-exit unless needed)
//    kernel3: fused elementwise apply with composed flip addressing.

#define B_    128
#define C_    3
#define H_    224
#define W_    224
#define N_ELEM (C_*H_*W_)        // 150528 per image
#define N4    (N_ELEM/4)         // 37632 float4 per image
#define W4    (W_/4)             // 56 float4 per row
#define HW4   (H_*W4)            // 12544 float4 per channel
#define S_    8                  // reduce blocks per image
#define CHUNK (N4/S_)            // 4704 float4 per reduce block
#define BPI   (N4/256)           // 147 apply blocks per image (147*256==37632)

__device__ __forceinline__ float apply_pw(float v, int tf, float mean) {
    switch (tf) {
        case 3: return fminf(fmaxf(v * 1.5f, 0.0f), 1.0f);                  // brightness
        case 4: return fminf(fmaxf((v - mean) * 1.5f + mean, 0.0f), 1.0f);  // contrast
        case 5: return (v < 0.5f) ? v : (1.0f - v);                         // solarize
        case 6: return 1.0f - v;                                            // invert
        case 7: return floorf(v * 4.0f) * 0.25f;                            // posterize
        default: return v;   // identity / flips (handled via addressing)
    }
}

__device__ __forceinline__ float block_reduce_sum(float v) {
    #pragma unroll
    for (int o = 32; o > 0; o >>= 1) v += __shfl_down(v, o, 64);
    __shared__ float smem[4];
    const int lane = threadIdx.x & 63, wid = threadIdx.x >> 6;
    if (lane == 0) smem[wid] = v;
    __syncthreads();
    return smem[0] + smem[1] + smem[2] + smem[3];  // valid for all threads
}

// Kernel 1: sum0[img] partials (only when a contrast mean may be needed).
__global__ __launch_bounds__(256) void k_reduce0(const float* __restrict__ x,
                                                 const int* __restrict__ samples,
                                                 float* __restrict__ partial0) {
    const int img = blockIdx.x / S_, blk = blockIdx.x % S_;
    const int t0 = samples[img], t1 = samples[B_ + img];
    if (!(t0 == 4 || t1 == 4)) return;           // mean0 never consumed
    const float4* xi = (const float4*)x + (size_t)img * N4;
    const int start = blk * CHUNK, end = start + CHUNK;
    float acc = 0.0f;
    for (int i = start + threadIdx.x; i < end; i += 256) {
        float4 v = xi[i];
        acc += (v.x + v.y) + (v.z + v.w);
    }
    float tot = block_reduce_sum(acc);
    if (threadIdx.x == 0) partial0[img * S_ + blk] = tot;
}

// Kernel 2: sum1[img] = sum(P0(x[img])) — only if t1==contrast and t0 pointwise.
__global__ __launch_bounds__(256) void k_reduce1(const float* __restrict__ x,
                                                 const int* __restrict__ samples,
                                                 const float* __restrict__ partial0,
                                                 float* __restrict__ partial1) {
    const int img = blockIdx.x / S_, blk = blockIdx.x % S_;
    const int t0 = samples[img], t1 = samples[B_ + img];
    if (!(t1 == 4 && t0 >= 3)) return;           // else mean1==mean0 or unused
    float mean0 = 0.0f;
    if (t0 == 4) {
        float s = 0.0f;
        #pragma unroll
        for (int i = 0; i < S_; ++i) s += partial0[img * S_ + i];
        mean0 = s * (1.0f / N_ELEM);
    }
    const float4* xi = (const float4*)x + (size_t)img * N4;
    const int start = blk * CHUNK, end = start + CHUNK;
    float acc = 0.0f;
    for (int i = start + threadIdx.x; i < end; i += 256) {
        float4 v = xi[i];
        acc += apply_pw(v.x, t0, mean0) + apply_pw(v.y, t0, mean0)
             + apply_pw(v.z, t0, mean0) + apply_pw(v.w, t0, mean0);
    }
    float tot = block_reduce_sum(acc);
    if (threadIdx.x == 0) partial1[img * S_ + blk] = tot;
}

// Kernel 3: fused apply. Composed flips at read address, P1(P0(v)) pointwise.
__global__ __launch_bounds__(256) void k_apply(const float* __restrict__ x,
                                               const int* __restrict__ samples,
                                               const float* __restrict__ partial0,
                                               const float* __restrict__ partial1,
                                               float* __restrict__ out) {
    const int img = blockIdx.x / BPI;
    const int t0 = samples[img], t1 = samples[B_ + img];

    __shared__ float means[2];
    if (threadIdx.x == 0) {
        float m0 = 0.0f, m1 = 0.0f;
        if (t0 == 4 || t1 == 4) {
            float s = 0.0f;
            #pragma unroll
            for (int i = 0; i < S_; ++i) s += partial0[img * S_ + i];
            m0 = s * (1.0f / N_ELEM);
        }
        if (t1 == 4) {
            if (t0 < 3) m1 = m0;                 // P0 is identity-valued
            else {
                float s = 0.0f;
                #pragma unroll
                for (int i = 0; i < S_; ++i) s += partial1[img * S_ + i];
                m1 = s * (1.0f / N_ELEM);
            }
        }
        means[0] = m0; means[1] = m1;
    }
    __syncthreads();
    const float m0 = means[0], m1 = means[1];

    const bool fw = (t0 == 1) ^ (t1 == 1);       // net flip along W
    const bool fh = (t0 == 2) ^ (t1 == 2);       // net flip along H

    const int tid = (blockIdx.x % BPI) * 256 + threadIdx.x;   // float4 idx, < N4
    const int c = tid / HW4, rem = tid % HW4;
    const int h = rem / W4, wq = rem % W4;
    const int hs  = fh ? (H_ - 1 - h)  : h;
    const int wqs = fw ? (W4 - 1 - wq) : wq;

    const float4* xi = (const float4*)x + (size_t)img * N4;
    float4 v = xi[c * HW4 + hs * W4 + wqs];
    if (fw) { float t = v.x; v.x = v.w; v.w = t; t = v.y; v.y = v.z; v.z = t; }

    v.x = apply_pw(apply_pw(v.x, t0, m0), t1, m1);
    v.y = apply_pw(apply_pw(v.y, t0, m0), t1, m1);
    v.z = apply_pw(apply_pw(v.z, t0, m0), t1, m1);
    v.w = apply_pw(apply_pw(v.w, t0, m0), t1, m1);

    ((float4*)out)[(size_t)img * N4 + tid] = v;
}

extern "C" void kernel_launch(void* const* d_in, const int* in_sizes, int n_in,
                              void* d_out, int out_size, void* d_ws, size_t ws_size,
                              hipStream_t stream) {
    const float* x       = (const float*)d_in[0];
    // d_in[1] (prob) is dead code in the reference.
    const int*   samples = (const int*)d_in[2];
    float*       out     = (float*)d_out;

    float* partial0 = (float*)d_ws;              // B_*S_ floats
    float* partial1 = partial0 + B_ * S_;        // B_*S_ floats  (8 KB total)

    k_reduce0<<<B_ * S_, 256, 0, stream>>>(x, samples, partial0);
    k_reduce1<<<B_ * S_, 256, 0, stream>>>(x, samples, partial0, partial1);
    k_apply  <<<B_ * BPI, 256, 0, stream>>>(x, samples, partial0, partial1, out);
}